// Round 1
// baseline (453.262 us; speedup 1.0000x reference)
//
#include <hip/hip_runtime.h>

#define N_NODES 8192
#define IN_F 256
#define OUT_F 128
#define ALPHA 0.5f

using short8 = __attribute__((ext_vector_type(8))) short;
using f32x4  = __attribute__((ext_vector_type(4))) float;

__device__ __forceinline__ unsigned short f2bf(float f){
  unsigned int u = __float_as_uint(f);
  u += 0x7fffu + ((u >> 16) & 1u);   // RNE
  return (unsigned short)(u >> 16);
}

// ---------------- K0: h = x @ W (fp32) ----------------
// grid 256 blocks x 256 thr; block = 32 rows. Each wave: 8 rows x 2 cols/lane.
// W read as float2/lane -> perfectly coalesced 512B/row; x broadcast from LDS.
__global__ __launch_bounds__(256) void k_h(const float* __restrict__ x,
                                           const float* __restrict__ W,
                                           float* __restrict__ h){
  __shared__ float xs[32*IN_F];
  const int tid = threadIdx.x;
  const int r0 = blockIdx.x * 32;
  const float4* xg = (const float4*)(x + (size_t)r0*IN_F);
  float4* xl = (float4*)xs;
  #pragma unroll
  for(int i=0;i<8;i++) xl[tid + i*256] = xg[tid + i*256];
  __syncthreads();
  const int wave = tid >> 6, lane = tid & 63;
  float2 acc[8];
  #pragma unroll
  for(int j=0;j<8;j++){ acc[j].x = 0.f; acc[j].y = 0.f; }
  const float2* Wp = (const float2*)W;       // W[k][c] -> float2 idx k*64+lane
  for(int k4=0;k4<IN_F;k4+=4){
    float4 xq[8];
    #pragma unroll
    for(int j=0;j<8;j++) xq[j] = *(const float4*)&xs[(wave*8+j)*IN_F + k4];
    #pragma unroll
    for(int kk=0;kk<4;kk++){
      float2 wv = Wp[(size_t)(k4+kk)*64 + lane];
      #pragma unroll
      for(int j=0;j<8;j++){
        float xv = kk==0?xq[j].x : kk==1?xq[j].y : kk==2?xq[j].z : xq[j].w;
        acc[j].x += xv*wv.x; acc[j].y += xv*wv.y;
      }
    }
  }
  #pragma unroll
  for(int j=0;j<8;j++)
    *(float2*)(h + (size_t)(r0 + wave*8 + j)*OUT_F + lane*2) = acc[j];
}

// ---------------- K1: f1 = h@a1, f2 = h@a2 ----------------
// one wave per row, shuffle reduce. grid 2048 x 256.
__global__ __launch_bounds__(256) void k_f(const float* __restrict__ h,
                                           const float* __restrict__ a,
                                           float* __restrict__ f1,
                                           float* __restrict__ f2){
  const int wave = threadIdx.x >> 6, lane = threadIdx.x & 63;
  const int row = blockIdx.x*4 + wave;
  float2 hv = ((const float2*)(h + (size_t)row*OUT_F))[lane];
  float2 a1 = ((const float2*)a)[lane];
  float2 a2 = ((const float2*)(a + OUT_F))[lane];
  float s1 = hv.x*a1.x + hv.y*a1.y;
  float s2 = hv.x*a2.x + hv.y*a2.y;
  #pragma unroll
  for(int off=32; off; off>>=1){
    s1 += __shfl_down(s1, off);
    s2 += __shfl_down(s2, off);
  }
  if(lane == 0){ f1[row] = s1; f2[row] = s2; }
}

// ---------------- K2: hT[c][r] = bf16(h[r][c]) ----------------
// 32x32 tiles via LDS. grid (4, 256) x 256.
__global__ __launch_bounds__(256) void k_t(const float* __restrict__ h,
                                           unsigned short* __restrict__ hT){
  __shared__ unsigned short tile[32*33];
  const int tid = threadIdx.x;
  const int c0 = blockIdx.x * 32;
  const int i0 = blockIdx.y * 32;
  const int i = tid >> 3, c4 = (tid & 7) * 4;
  float4 v = *(const float4*)(h + (size_t)(i0+i)*OUT_F + c0 + c4);
  tile[(c4+0)*33 + i] = f2bf(v.x);
  tile[(c4+1)*33 + i] = f2bf(v.y);
  tile[(c4+2)*33 + i] = f2bf(v.z);
  tile[(c4+3)*33 + i] = f2bf(v.w);
  __syncthreads();
  const int c = tid >> 3, i4 = (tid & 7) * 4;
  ushort4 o;
  o.x = tile[c*33 + i4 + 0];
  o.y = tile[c*33 + i4 + 1];
  o.z = tile[c*33 + i4 + 2];
  o.w = tile[c*33 + i4 + 3];
  *(ushort4*)(hT + (size_t)(c0+c)*N_NODES + i0 + i4) = o;
}

// ---------------- K3: fused masked-exp + attn@h (partials) ----------------
// grid (4 j-chunks, 256 row-tiles) x 256 thr. Block: 32 rows, sweeps 2048 j in
// 32 steps of BK=64. w tile (32x64 bf16) in LDS (row stride 72 shorts = 144B,
// 16B aligned, 2-way-free banks). 4 waves x (M32 x N32) via 16x16x32 bf16 MFMA.
__global__ __launch_bounds__(256) void k_attn(const int* __restrict__ adj,
    const unsigned short* __restrict__ hT,
    const float* __restrict__ f1, const float* __restrict__ f2,
    float* __restrict__ accg, float* __restrict__ deng){
  __shared__ short wlds[32*72];
  __shared__ float dls[256];
  const int tid = threadIdx.x;
  const int r0 = blockIdx.y * 32;
  const int jbase = blockIdx.x * 2048;
  const int r = tid >> 3, g = tid & 7;          // writer: row r, k-octet g
  const int wave = tid >> 6, lane = tid & 63;
  const int arow = lane & 15, aq = lane >> 4;   // MFMA frag coords
  const int n0 = wave * 32;                     // this wave's feature cols
  const float rowf1 = f1[r0 + r];
  float den = 0.f;
  f32x4 acc00 = {0,0,0,0}, acc01 = {0,0,0,0}, acc10 = {0,0,0,0}, acc11 = {0,0,0,0};
  const int* adjrow = adj + (size_t)(r0+r)*N_NODES + g*8;
  const unsigned short* hT0 = hT + (size_t)(n0      + arow)*N_NODES + aq*8;
  const unsigned short* hT1 = hT + (size_t)(n0 + 16 + arow)*N_NODES + aq*8;
  short* wsrow = &wlds[r*72 + g*8];
  const short* ar0 = &wlds[ arow     *72 + aq*8];
  const short* ar1 = &wlds[(arow+16) *72 + aq*8];

  auto wfun = [&](int aval, float f2v) -> float {
    float tt = rowf1 + f2v;
    float ee = tt > 0.f ? tt : ALPHA * tt;      // leaky_relu, slope 0.5
    float w  = aval > 0 ? __expf(ee) : 0.f;     // bounded: no max-shift needed
    den += w;
    return w;
  };

  for(int s=0; s<32; s++){
    const int k0 = jbase + s*64;
    int4 av0 = *(const int4*)(adjrow + k0);       // 32B contig per thread
    int4 av1 = *(const int4*)(adjrow + k0 + 4);
    float4 fa = *(const float4*)(f2 + k0 + g*8);  // L2-hot
    float4 fb = *(const float4*)(f2 + k0 + g*8 + 4);
    short8 wv;
    wv[0] = (short)f2bf(wfun(av0.x, fa.x));
    wv[1] = (short)f2bf(wfun(av0.y, fa.y));
    wv[2] = (short)f2bf(wfun(av0.z, fa.z));
    wv[3] = (short)f2bf(wfun(av0.w, fa.w));
    wv[4] = (short)f2bf(wfun(av1.x, fb.x));
    wv[5] = (short)f2bf(wfun(av1.y, fb.y));
    wv[6] = (short)f2bf(wfun(av1.z, fb.z));
    wv[7] = (short)f2bf(wfun(av1.w, fb.w));
    __syncthreads();                 // prior MFMA reads of wlds done
    *(short8*)wsrow = wv;
    __syncthreads();                 // w tile visible
    #pragma unroll
    for(int kk=0; kk<2; kk++){
      short8 A0 = *(const short8*)(ar0 + kk*32);
      short8 A1 = *(const short8*)(ar1 + kk*32);
      short8 B0 = *(const short8*)(hT0 + k0 + kk*32);
      short8 B1 = *(const short8*)(hT1 + k0 + kk*32);
      acc00 = __builtin_amdgcn_mfma_f32_16x16x32_bf16(A0, B0, acc00, 0,0,0);
      acc01 = __builtin_amdgcn_mfma_f32_16x16x32_bf16(A0, B1, acc01, 0,0,0);
      acc10 = __builtin_amdgcn_mfma_f32_16x16x32_bf16(A1, B0, acc10, 0,0,0);
      acc11 = __builtin_amdgcn_mfma_f32_16x16x32_bf16(A1, B1, acc11, 0,0,0);
    }
  }

  // denominator partials: 8 threads/row -> LDS -> one atomic per row
  dls[tid] = den;
  __syncthreads();
  if(tid < 32){
    float sden = 0.f;
    #pragma unroll
    for(int i=0;i<8;i++) sden += dls[tid*8 + i];
    atomicAdd(deng + r0 + tid, sden);
  }
  // accumulator partials. C/D layout (m89): col=lane&15, row=aq*4+reg
  #pragma unroll
  for(int reg=0; reg<4; reg++){
    const int m = aq*4 + reg;
    atomicAdd(accg + (size_t)(r0 + m     )*OUT_F + n0      + arow, acc00[reg]);
    atomicAdd(accg + (size_t)(r0 + m     )*OUT_F + n0 + 16 + arow, acc01[reg]);
    atomicAdd(accg + (size_t)(r0 + 16 + m)*OUT_F + n0      + arow, acc10[reg]);
    atomicAdd(accg + (size_t)(r0 + 16 + m)*OUT_F + n0 + 16 + arow, acc11[reg]);
  }
}

// ---------------- K4: out = elu(acc/den) ----------------
__global__ __launch_bounds__(256) void k_out(const float* __restrict__ accg,
    const float* __restrict__ deng, float* __restrict__ out){
  const int idx = blockIdx.x*256 + threadIdx.x;
  const float v = accg[idx] / deng[idx >> 7];
  out[idx] = v > 0.f ? v : (__expf(v) - 1.f);
}

extern "C" void kernel_launch(void* const* d_in, const int* in_sizes, int n_in,
                              void* d_out, int out_size, void* d_ws, size_t ws_size,
                              hipStream_t stream){
  const float* x   = (const float*)d_in[0];
  const int*   adj = (const int*)d_in[1];
  const float* W   = (const float*)d_in[2];
  const float* a   = (const float*)d_in[3];
  char* ws = (char*)d_ws;
  // ws layout: [0,4MB) h fp32 (later aliased as acc), [4MB,6MB) hT bf16,
  // then f1 (32KB), f2 (32KB), den (32KB). Total ~6.1 MB.
  float* h            = (float*)ws;
  unsigned short* hT  = (unsigned short*)(ws + (4u<<20));
  float* f1           = (float*)(ws + (6u<<20));
  float* f2           = (float*)(ws + (6u<<20) + (32u<<10));
  float* den          = (float*)(ws + (6u<<20) + (64u<<10));
  float* accg         = h;   // alias: h no longer needed after k_t
  float* out          = (float*)d_out;

  k_h<<<256, 256, 0, stream>>>(x, W, h);
  k_f<<<2048, 256, 0, stream>>>(h, a, f1, f2);
  k_t<<<dim3(4,256), 256, 0, stream>>>(h, hT);
  hipMemsetAsync(accg, 0, (size_t)N_NODES*OUT_F*sizeof(float), stream);
  hipMemsetAsync(den, 0, (size_t)N_NODES*sizeof(float), stream);
  k_attn<<<dim3(4,256), 256, 0, stream>>>(adj, hT, f1, f2, accg, den);
  k_out<<<(N_NODES*OUT_F)/256, 256, 0, stream>>>(accg, den, out);
}